// Round 10
// baseline (164.886 us; speedup 1.0000x reference)
//
#include <hip/hip_runtime.h>
#include <math.h>

// ListNet segment-softmax CE — ROUND 10: ablation round (deliberate).
// Real pipeline: r5 structure (K=16 serial walk) + AoS slot layout fixing the
// 4-way same-bank flush conflict (SLOTS%32==0 made lel/les/ltl/lcnt[s] all hit
// bank s%32 in rounds 3-9). Then 4 ablation dispatches (dummy ws, 4 reps each
// so they beat the ~39us harness fills into top-5):
//   ablate<0> loads only | <1> +walk no LDS | <2> +SoA flush (r5 layout)
//   | <3> +AoS flush. Deltas decompose load/walk/flush/bank costs.

#define TPB 256
#define K 16
#define CHUNK (TPB * K)   // 4096 items per block
#define SLOTS 768
#define REPS 4

struct __align__(16) Slot { float el, es, tl; int cnt; };

// ---- 12 vector loads for a thread's 16-item window (expects tid, base) ----
#define LOAD16()                                                               \
    const int t0 = base + tid * K;                                             \
    const int4   wA = *reinterpret_cast<const int4*>(widx + t0);               \
    const int4   wB = *reinterpret_cast<const int4*>(widx + t0 + 4);           \
    const int4   wC = *reinterpret_cast<const int4*>(widx + t0 + 8);           \
    const int4   wD = *reinterpret_cast<const int4*>(widx + t0 + 12);          \
    const float4 lA = *reinterpret_cast<const float4*>(labels + t0);           \
    const float4 lB = *reinterpret_cast<const float4*>(labels + t0 + 4);       \
    const float4 lC = *reinterpret_cast<const float4*>(labels + t0 + 8);       \
    const float4 lD = *reinterpret_cast<const float4*>(labels + t0 + 12);      \
    const float4 sA = *reinterpret_cast<const float4*>(scores + t0);           \
    const float4 sB = *reinterpret_cast<const float4*>(scores + t0 + 4);       \
    const float4 sC = *reinterpret_cast<const float4*>(scores + t0 + 8);       \
    const float4 sD = *reinterpret_cast<const float4*>(scores + t0 + 12);

#define ITEM(wv_, lv_, sv_)                                                    \
    {                                                                          \
        const float el = __expf(lv_), es = __expf(sv_);                        \
        if ((wv_) == cw) { ra += el; rb += es; rt += el * (sv_); ++rc; }       \
        else {                                                                 \
            if (!head_saved) {                                                 \
                hs = cw - w0; ha = ra; hb = rb; ht = rt; hc = rc;              \
                head_saved = true;                                             \
            } else if (rc >= 2) {                                              \
                loss += rt / ra - __logf(rb); ++nv;                            \
            }                                                                  \
            cw = (wv_); ra = el; rb = es; rt = el * (sv_); rc = 1;             \
        }                                                                      \
    }

#define WALK16()                                                               \
    int cw; float ra, rb, rt; int rc;                                          \
    bool head_saved = false;                                                   \
    int hs = 0; float ha = 0.f, hb = 0.f, ht = 0.f; int hc = 0;                \
    {                                                                          \
        const float el = __expf(lA.x), es = __expf(sA.x);                      \
        cw = wA.x; ra = el; rb = es; rt = el * sA.x; rc = 1;                   \
    }                                                                          \
    ITEM(wA.y, lA.y, sA.y) ITEM(wA.z, lA.z, sA.z) ITEM(wA.w, lA.w, sA.w)       \
    ITEM(wB.x, lB.x, sB.x) ITEM(wB.y, lB.y, sB.y) ITEM(wB.z, lB.z, sB.z)       \
    ITEM(wB.w, lB.w, sB.w)                                                     \
    ITEM(wC.x, lC.x, sC.x) ITEM(wC.y, lC.y, sC.y) ITEM(wC.z, lC.z, sC.z)       \
    ITEM(wC.w, lC.w, sC.w)                                                     \
    ITEM(wD.x, lD.x, sD.x) ITEM(wD.y, lD.y, sD.y) ITEM(wD.z, lD.z, sD.z)       \
    ITEM(wD.w, lD.w, sD.w)

// ---------------- real pipeline: r5 + AoS bank fix ----------------
__global__ __launch_bounds__(TPB) void main_pass(
        const float* __restrict__ scores, const float* __restrict__ labels,
        const int* __restrict__ widx,
        int* __restrict__ rec_week, float* __restrict__ rec_el,
        float* __restrict__ rec_es, float* __restrict__ rec_tl,
        int* __restrict__ rec_cnt,
        float* __restrict__ part_loss, int* __restrict__ part_nv) {
    __shared__ Slot slot[SLOTS];
    __shared__ float ra4[4];
    __shared__ int   rn4[4];
    const int tid = threadIdx.x;
    const int lane = tid & 63, wv = tid >> 6;
    const int base = blockIdx.x * CHUNK;

    LOAD16()                                  // issue all 12 loads up-front
    const int w0 = widx[base];
    const int wl = widx[base + CHUNK - 1];
    const int span = wl - w0;
    for (int s = tid; s <= span; s += TPB) {  // init live slots while loads fly
        slot[s].el = 0.f; slot[s].es = 0.f; slot[s].tl = 0.f; slot[s].cnt = 0;
    }
    __syncthreads();

    float loss = 0.f; int nv = 0;
    WALK16()
    if (head_saved) {
        atomicAdd(&slot[hs].el, ha); atomicAdd(&slot[hs].es, hb);
        atomicAdd(&slot[hs].tl, ht); atomicAdd(&slot[hs].cnt, hc);
    }
    const int ts = cw - w0;
    atomicAdd(&slot[ts].el, ra); atomicAdd(&slot[ts].es, rb);
    atomicAdd(&slot[ts].tl, rt); atomicAdd(&slot[ts].cnt, rc);
    __syncthreads();

    for (int s = 1 + tid; s < span; s += TPB) {
        if (slot[s].cnt >= 2) {
            loss += slot[s].tl / slot[s].el - __logf(slot[s].es); ++nv;
        }
    }
    #pragma unroll
    for (int off = 32; off; off >>= 1) {
        loss += __shfl_down(loss, off);
        nv   += __shfl_down(nv, off);
    }
    if (lane == 0) { ra4[wv] = loss; rn4[wv] = nv; }
    __syncthreads();
    if (tid == 0) {
        part_loss[blockIdx.x] = ra4[0] + ra4[1] + ra4[2] + ra4[3];
        part_nv[blockIdx.x]   = rn4[0] + rn4[1] + rn4[2] + rn4[3];
        const int b2 = blockIdx.x * 2;
        rec_week[b2] = w0;
        rec_el[b2] = slot[0].el; rec_es[b2] = slot[0].es;
        rec_tl[b2] = slot[0].tl; rec_cnt[b2] = slot[0].cnt;
        rec_week[b2 + 1] = wl;
        if (span > 0) {
            rec_el[b2 + 1] = slot[span].el; rec_es[b2 + 1] = slot[span].es;
            rec_tl[b2 + 1] = slot[span].tl; rec_cnt[b2 + 1] = slot[span].cnt;
        } else {
            rec_el[b2 + 1] = 0.f; rec_es[b2 + 1] = 0.f;
            rec_tl[b2 + 1] = 0.f; rec_cnt[b2 + 1] = 0;
        }
    }
}

__global__ __launch_bounds__(1024) void finalize(
        const int* __restrict__ rec_week, const float* __restrict__ rec_el,
        const float* __restrict__ rec_es, const float* __restrict__ rec_tl,
        const int* __restrict__ rec_cnt,
        const float* __restrict__ part_loss, const int* __restrict__ part_nv,
        int nrec, int nb, float* __restrict__ out) {
    const int tid = threadIdx.x;
    float loss = 0.f; int nv = 0;
    for (int j = tid; j < nrec; j += 1024) {
        const int w = rec_week[j];
        if (j > 0 && rec_week[j - 1] == w) continue;
        float a = rec_el[j], b = rec_es[j], t = rec_tl[j];
        int c = rec_cnt[j];
        for (int k = j + 1; k < nrec && rec_week[k] == w; ++k) {
            a += rec_el[k]; b += rec_es[k]; t += rec_tl[k]; c += rec_cnt[k];
        }
        if (c >= 2) { loss += t / a - __logf(b); ++nv; }
    }
    for (int j = tid; j < nb; j += 1024) { loss += part_loss[j]; nv += part_nv[j]; }
    #pragma unroll
    for (int off = 32; off; off >>= 1) {
        loss += __shfl_down(loss, off);
        nv   += __shfl_down(nv, off);
    }
    __shared__ float ra[16];
    __shared__ int   rn[16];
    const int lane = tid & 63, wv = tid >> 6;
    if (lane == 0) { ra[wv] = loss; rn[wv] = nv; }
    __syncthreads();
    if (tid == 0) {
        float tl = 0.f; int tn = 0;
        for (int k = 0; k < 16; ++k) { tl += ra[k]; tn += rn[k]; }
        out[0] = (tn > 0) ? (-tl / (float)tn) : 0.f;
    }
}

// ---------------- ablation kernels (dummy output, 4 reps) ----------------
// MODE 0: loads only | 1: +walk (no LDS) | 2: +SoA flush (r3-r9 bank layout)
// | 3: +AoS flush (bank-fixed)
template <int MODE>
__global__ __launch_bounds__(TPB) void ablate(
        const float* __restrict__ scores, const float* __restrict__ labels,
        const int* __restrict__ widx, float* __restrict__ dummy) {
    __shared__ float soa[(MODE == 2) ? SLOTS * 4 : 4];
    __shared__ Slot  aos[(MODE == 3) ? SLOTS : 1];
    const int tid = threadIdx.x;
    const int base = blockIdx.x * CHUNK;
    const int w0 = widx[base];
    const int wl = widx[base + CHUNK - 1];
    const int span = wl - w0;
    float acc = 0.f;

    #pragma unroll 1
    for (int rep = 0; rep < REPS; ++rep) {
        asm volatile("" ::: "memory");   // force re-load each rep (no hoist)
        LOAD16()
        if constexpr (MODE == 0) {
            const int ix = wA.x ^ wA.y ^ wA.z ^ wA.w ^ wB.x ^ wB.y ^ wB.z ^ wB.w
                         ^ wC.x ^ wC.y ^ wC.z ^ wC.w ^ wD.x ^ wD.y ^ wD.z ^ wD.w;
            acc += (float)ix
                 + lA.x + lA.y + lA.z + lA.w + lB.x + lB.y + lB.z + lB.w
                 + lC.x + lC.y + lC.z + lC.w + lD.x + lD.y + lD.z + lD.w
                 + sA.x + sA.y + sA.z + sA.w + sB.x + sB.y + sB.z + sB.w
                 + sC.x + sC.y + sC.z + sC.w + sD.x + sD.y + sD.z + sD.w;
        } else {
            if constexpr (MODE == 2) {
                for (int s = tid; s <= span; s += TPB) {
                    soa[s] = 0.f; soa[SLOTS + s] = 0.f;
                    soa[2 * SLOTS + s] = 0.f; soa[3 * SLOTS + s] = 0.f;
                }
                __syncthreads();
            }
            if constexpr (MODE == 3) {
                for (int s = tid; s <= span; s += TPB) {
                    aos[s].el = 0.f; aos[s].es = 0.f; aos[s].tl = 0.f; aos[s].cnt = 0;
                }
                __syncthreads();
            }
            float loss = 0.f; int nv = 0;
            WALK16()
            if constexpr (MODE == 1) {
                if (head_saved) acc += ha + hb + ht + (float)hc + (float)hs;
                acc += ra + rb + rt + (float)rc + (float)cw;
            } else if constexpr (MODE == 2) {
                if (head_saved) {
                    atomicAdd(&soa[hs], ha); atomicAdd(&soa[SLOTS + hs], hb);
                    atomicAdd(&soa[2 * SLOTS + hs], ht);
                    atomicAdd(&soa[3 * SLOTS + hs], (float)hc);
                }
                const int ts = cw - w0;
                atomicAdd(&soa[ts], ra); atomicAdd(&soa[SLOTS + ts], rb);
                atomicAdd(&soa[2 * SLOTS + ts], rt);
                atomicAdd(&soa[3 * SLOTS + ts], (float)rc);
            } else if constexpr (MODE == 3) {
                if (head_saved) {
                    atomicAdd(&aos[hs].el, ha); atomicAdd(&aos[hs].es, hb);
                    atomicAdd(&aos[hs].tl, ht); atomicAdd(&aos[hs].cnt, hc);
                }
                const int ts = cw - w0;
                atomicAdd(&aos[ts].el, ra); atomicAdd(&aos[ts].es, rb);
                atomicAdd(&aos[ts].tl, rt); atomicAdd(&aos[ts].cnt, rc);
            }
            if constexpr (MODE == 2) {
                __syncthreads();
                for (int s = 1 + tid; s < span; s += TPB) {
                    if (soa[3 * SLOTS + s] >= 2.f) {
                        acc += soa[2 * SLOTS + s] / soa[s] - __logf(soa[SLOTS + s]) + 1.f;
                    }
                }
                __syncthreads();
            }
            if constexpr (MODE == 3) {
                __syncthreads();
                for (int s = 1 + tid; s < span; s += TPB) {
                    if (aos[s].cnt >= 2) {
                        acc += aos[s].tl / aos[s].el - __logf(aos[s].es) + 1.f;
                    }
                }
                __syncthreads();
            }
            acc += loss + (float)nv;
        }
    }
    dummy[blockIdx.x] = acc;   // keep everything live
}

extern "C" void kernel_launch(void* const* d_in, const int* in_sizes, int n_in,
                              void* d_out, int out_size, void* d_ws, size_t ws_size,
                              hipStream_t stream) {
    const float* scores = (const float*)d_in[0];
    const float* labels = (const float*)d_in[1];
    const int*   widx   = (const int*)d_in[2];
    const int n  = in_sizes[0];
    const int nb = n / CHUNK;      // 1024
    const int nrec = nb * 2;

    char* ws = (char*)d_ws;
    size_t off = 0;
    int*   rec_week = (int*)  (ws + off); off += (size_t)nrec * 4;
    float* rec_el   = (float*)(ws + off); off += (size_t)nrec * 4;
    float* rec_es   = (float*)(ws + off); off += (size_t)nrec * 4;
    float* rec_tl   = (float*)(ws + off); off += (size_t)nrec * 4;
    int*   rec_cnt  = (int*)  (ws + off); off += (size_t)nrec * 4;
    float* part_loss= (float*)(ws + off); off += (size_t)nb * 4;
    int*   part_nv  = (int*)  (ws + off);
    float* dum = (float*)(ws + 262144);   // 4 x 4KB dummy slices at 256KB

    float* out = (float*)d_out;

    main_pass<<<nb, TPB, 0, stream>>>(scores, labels, widx,
                                      rec_week, rec_el, rec_es, rec_tl, rec_cnt,
                                      part_loss, part_nv);
    finalize<<<1, 1024, 0, stream>>>(rec_week, rec_el, rec_es, rec_tl, rec_cnt,
                                     part_loss, part_nv, nrec, nb, out);
    // ---- ablation dispatches (output already written; dummy ws only) ----
    ablate<0><<<nb, TPB, 0, stream>>>(scores, labels, widx, dum);
    ablate<1><<<nb, TPB, 0, stream>>>(scores, labels, widx, dum + 1024);
    ablate<2><<<nb, TPB, 0, stream>>>(scores, labels, widx, dum + 2048);
    ablate<3><<<nb, TPB, 0, stream>>>(scores, labels, widx, dum + 3072);
}

// Round 11
// 32.859 us; speedup vs baseline: 5.0180x; 5.0180x over previous
//
#include <hip/hip_runtime.h>
#include <math.h>

// ListNet segment-softmax CE, sorted week indices.
// BATCH = 4194304, NUM_WEEKS = 262144, avg 16 items/week.
//
// Per-week loss = T/S_l - log(S_s);  S_l = sum e^l, S_s = sum e^s, T = sum e^l*s.
// (eps inside log dropped; validated rounds 2-10, absmax 0.0)
//
// Round-11 (r10 ablation: latency-bound — VALU 18%, HBM 17%, occ 33%):
//  - single-WAVE blocks (TPB=64, CHUNK=1024, 4096 blocks): independent
//    retirement, no multi-wave barriers, finer-grain load balance; w0/wl via
//    __shfl (saves 2 broadcast loads).
//  - 16-item walk split into TWO independent 8-item chains (halved dependent
//    chain, 2x ILP) merged via a 4-run append.
//  - flush rate stays r5's 0.125 groups/item; AoS slots (r10: bank layout
//    neutral, conflicts 0).

#define TPB 64
#define K 16
#define CHUNK (TPB * K)   // 1024 items per block
#define SLOTS 256         // > max span+1 (mean ~64, 4x margin, r5-proportional)

struct __align__(16) Slot { float el, es, tl; int cnt; };
struct Run { int w; float a, b, t; int c; };

__device__ __forceinline__ void chain8(
        const int4& w1, const int4& w2,
        const float4& l1, const float4& l2,
        const float4& s1, const float4& s2,
        Run& head, bool& saved, Run& tail, float& loss, int& nv) {
    saved = false;
    Run r;
    {
        const float el = __expf(l1.x), es = __expf(s1.x);
        r.w = w1.x; r.a = el; r.b = es; r.t = el * s1.x; r.c = 1;
    }
    auto item = [&](int wv, float lv, float sv) {
        const float el = __expf(lv), es = __expf(sv);
        if (wv == r.w) { r.a += el; r.b += es; r.t += el * sv; ++r.c; }
        else {
            if (!saved) { head = r; saved = true; }
            else if (r.c >= 2) { loss += r.t / r.a - __logf(r.b); ++nv; }
            r.w = wv; r.a = el; r.b = es; r.t = el * sv; r.c = 1;
        }
    };
    item(w1.y, l1.y, s1.y); item(w1.z, l1.z, s1.z); item(w1.w, l1.w, s1.w);
    item(w2.x, l2.x, s2.x); item(w2.y, l2.y, s2.y); item(w2.z, l2.z, s2.z);
    item(w2.w, l2.w, s2.w);
    tail = r;
}

__global__ __launch_bounds__(TPB) void main_pass(
        const float* __restrict__ scores, const float* __restrict__ labels,
        const int* __restrict__ widx,
        int* __restrict__ rec_week, float* __restrict__ rec_el,
        float* __restrict__ rec_es, float* __restrict__ rec_tl,
        int* __restrict__ rec_cnt,
        float* __restrict__ part_loss, int* __restrict__ part_nv) {
    __shared__ Slot slot[SLOTS];
    const int tid = threadIdx.x;            // == lane (one wave per block)
    const int base = blockIdx.x * CHUNK;
    const int t0 = base + tid * K;

    const int4   wA = *reinterpret_cast<const int4*>(widx + t0);
    const int4   wB = *reinterpret_cast<const int4*>(widx + t0 + 4);
    const int4   wC = *reinterpret_cast<const int4*>(widx + t0 + 8);
    const int4   wD = *reinterpret_cast<const int4*>(widx + t0 + 12);
    const float4 lA = *reinterpret_cast<const float4*>(labels + t0);
    const float4 lB = *reinterpret_cast<const float4*>(labels + t0 + 4);
    const float4 lC = *reinterpret_cast<const float4*>(labels + t0 + 8);
    const float4 lD = *reinterpret_cast<const float4*>(labels + t0 + 12);
    const float4 sA = *reinterpret_cast<const float4*>(scores + t0);
    const float4 sB = *reinterpret_cast<const float4*>(scores + t0 + 4);
    const float4 sC = *reinterpret_cast<const float4*>(scores + t0 + 8);
    const float4 sD = *reinterpret_cast<const float4*>(scores + t0 + 12);

    const int w0 = __shfl(wA.x, 0);         // block-uniform, no extra load
    const int wl = __shfl(wD.w, TPB - 1);
    const int span = wl - w0;

    for (int s = tid; s <= span; s += TPB) {
        slot[s].el = 0.f; slot[s].es = 0.f; slot[s].tl = 0.f; slot[s].cnt = 0;
    }
    __syncthreads();                        // 1-wave: compiles to cheap waitcnt

    float loss = 0.f; int nv = 0;
    Run hA, tA, hB, tB;
    bool sv1, sv2;
    chain8(wA, wB, lA, lB, sA, sB, hA, sv1, tA, loss, nv);
    chain8(wC, wD, lC, lD, sC, sD, hB, sv2, tB, loss, nv);

    // merge the two chains' boundary runs (items contiguous: tailA adj headB)
    Run th, cur; bool th_saved = false;
    cur = sv1 ? hA : tA;
    auto append = [&](const Run& run) {
        if (run.w == cur.w) {
            cur.a += run.a; cur.b += run.b; cur.t += run.t; cur.c += run.c;
        } else {
            if (!th_saved) { th = cur; th_saved = true; }
            else if (cur.c >= 2) { loss += cur.t / cur.a - __logf(cur.b); ++nv; }
            cur = run;
        }
    };
    if (sv1) append(tA);
    if (sv2) append(hB);
    append(tB);

    if (th_saved) {
        const int s = th.w - w0;
        atomicAdd(&slot[s].el, th.a); atomicAdd(&slot[s].es, th.b);
        atomicAdd(&slot[s].tl, th.t); atomicAdd(&slot[s].cnt, th.c);
    }
    {
        const int s = cur.w - w0;
        atomicAdd(&slot[s].el, cur.a); atomicAdd(&slot[s].es, cur.b);
        atomicAdd(&slot[s].tl, cur.t); atomicAdd(&slot[s].cnt, cur.c);
    }
    __syncthreads();

    // block-interior slots (strictly between w0 and wl) complete here
    for (int s = 1 + tid; s < span; s += TPB) {
        if (slot[s].cnt >= 2) {
            loss += slot[s].tl / slot[s].el - __logf(slot[s].es); ++nv;
        }
    }
    #pragma unroll
    for (int off = 32; off; off >>= 1) {
        loss += __shfl_down(loss, off);
        nv   += __shfl_down(nv, off);
    }
    if (tid == 0) {
        part_loss[blockIdx.x] = loss;
        part_nv[blockIdx.x]   = nv;
        const int b2 = blockIdx.x * 2;
        rec_week[b2] = w0;
        rec_el[b2] = slot[0].el; rec_es[b2] = slot[0].es;
        rec_tl[b2] = slot[0].tl; rec_cnt[b2] = slot[0].cnt;
        rec_week[b2 + 1] = wl;
        if (span > 0) {
            rec_el[b2 + 1] = slot[span].el; rec_es[b2 + 1] = slot[span].es;
            rec_tl[b2 + 1] = slot[span].tl; rec_cnt[b2 + 1] = slot[span].cnt;
        } else {  // single-week block: zero filler keeps run-adjacency intact
            rec_el[b2 + 1] = 0.f; rec_es[b2 + 1] = 0.f;
            rec_tl[b2 + 1] = 0.f; rec_cnt[b2 + 1] = 0;
        }
    }
}

__global__ __launch_bounds__(1024) void finalize(
        const int* __restrict__ rec_week, const float* __restrict__ rec_el,
        const float* __restrict__ rec_es, const float* __restrict__ rec_tl,
        const int* __restrict__ rec_cnt,
        const float* __restrict__ part_loss, const int* __restrict__ part_nv,
        int nrec, int nb, float* __restrict__ out) {
    const int tid = threadIdx.x;
    float loss = 0.f; int nv = 0;
    for (int j = tid; j < nrec; j += 1024) {
        const int w = rec_week[j];
        if (j > 0 && rec_week[j - 1] == w) continue;  // not a run head
        float a = rec_el[j], b = rec_es[j], t = rec_tl[j];
        int c = rec_cnt[j];
        for (int k = j + 1; k < nrec && rec_week[k] == w; ++k) {
            a += rec_el[k]; b += rec_es[k]; t += rec_tl[k]; c += rec_cnt[k];
        }
        if (c >= 2) { loss += t / a - __logf(b); ++nv; }
    }
    for (int j = tid; j < nb; j += 1024) { loss += part_loss[j]; nv += part_nv[j]; }
    #pragma unroll
    for (int off = 32; off; off >>= 1) {
        loss += __shfl_down(loss, off);
        nv   += __shfl_down(nv, off);
    }
    __shared__ float ra[16];
    __shared__ int   rn[16];
    const int lane = tid & 63, wv = tid >> 6;
    if (lane == 0) { ra[wv] = loss; rn[wv] = nv; }
    __syncthreads();
    if (tid == 0) {
        float tl = 0.f; int tn = 0;
        for (int k = 0; k < 16; ++k) { tl += ra[k]; tn += rn[k]; }
        out[0] = (tn > 0) ? (-tl / (float)tn) : 0.f;
    }
}

extern "C" void kernel_launch(void* const* d_in, const int* in_sizes, int n_in,
                              void* d_out, int out_size, void* d_ws, size_t ws_size,
                              hipStream_t stream) {
    const float* scores = (const float*)d_in[0];
    const float* labels = (const float*)d_in[1];
    const int*   widx   = (const int*)d_in[2];
    const int n  = in_sizes[0];
    const int nb = n / CHUNK;      // 4096
    const int nrec = nb * 2;

    char* ws = (char*)d_ws;
    size_t off = 0;
    int*   rec_week = (int*)  (ws + off); off += (size_t)nrec * 4;
    float* rec_el   = (float*)(ws + off); off += (size_t)nrec * 4;
    float* rec_es   = (float*)(ws + off); off += (size_t)nrec * 4;
    float* rec_tl   = (float*)(ws + off); off += (size_t)nrec * 4;
    int*   rec_cnt  = (int*)  (ws + off); off += (size_t)nrec * 4;
    float* part_loss= (float*)(ws + off); off += (size_t)nb * 4;
    int*   part_nv  = (int*)  (ws + off);

    float* out = (float*)d_out;

    main_pass<<<nb, TPB, 0, stream>>>(scores, labels, widx,
                                      rec_week, rec_el, rec_es, rec_tl, rec_cnt,
                                      part_loss, part_nv);
    finalize<<<1, 1024, 0, stream>>>(rec_week, rec_el, rec_es, rec_tl, rec_cnt,
                                     part_loss, part_nv, nrec, nb, out);
}